// Round 9
// baseline (265.142 us; speedup 1.0000x reference)
//
#include <hip/hip_runtime.h>
#include <hip/hip_bf16.h>
#include <stdint.h>

#define HIDDEN  1024
#define FFN_DIM 2048
#define NEXP    8
#define NTOK    2048          // B*S
#define MAXROWS 5120          // sum of 128-padded per-expert counts

typedef short bf16x8 __attribute__((ext_vector_type(8)));
typedef float f32x4  __attribute__((ext_vector_type(4)));

// ---------------- ws layout (bytes) ----------------
static const size_t OFF_CNT  = 0;                         // 8 ints
static const size_t OFF_BASE = 64;                        // 9 ints
static const size_t OFF_TOK  = 128;                       // 8*2048 ints
static const size_t OFF_WGT  = OFF_TOK + (size_t)NEXP*NTOK*4;
static const size_t OFF_XBF  = 131328;                    // 256-aligned
static const size_t XBF_B    = (size_t)NTOK*HIDDEN*2;
static const size_t OFF_W1B  = OFF_XBF + XBF_B;
static const size_t W_B      = (size_t)NEXP*FFN_DIM*HIDDEN*2;
static const size_t OFF_W3B  = OFF_W1B + W_B;
static const size_t OFF_W2B  = OFF_W3B + W_B;
static const size_t OFF_H    = OFF_W2B + W_B;
static const size_t H_B      = (size_t)MAXROWS*FFN_DIM*2;
static const size_t WS_NEED  = OFF_H + H_B;               // ~126 MB

__device__ __forceinline__ unsigned short f2bf(float f) {
  union { float f; unsigned u; } a; a.f = f;
  unsigned r = a.u + 0x7fff + ((a.u >> 16) & 1);          // RTN-even
  return (unsigned short)(r >> 16);
}

// 8 fp32 -> 8 bf16 packed into uint4 (memory order preserved)
__device__ __forceinline__ uint4 cvt8u(float4 a, float4 b) {
  uint4 r;
  asm("v_cvt_pk_bf16_f32 %0, %1, %2" : "=v"(r.x) : "v"(a.x), "v"(a.y));
  asm("v_cvt_pk_bf16_f32 %0, %1, %2" : "=v"(r.y) : "v"(a.z), "v"(a.w));
  asm("v_cvt_pk_bf16_f32 %0, %1, %2" : "=v"(r.z) : "v"(b.x), "v"(b.y));
  asm("v_cvt_pk_bf16_f32 %0, %1, %2" : "=v"(r.w) : "v"(b.z), "v"(b.w));
  return r;
}

__device__ __forceinline__ void ld_g2l16(const void* gsrc, void* ldst) {
  __builtin_amdgcn_global_load_lds(
      (const __attribute__((address_space(1))) unsigned int*)gsrc,
      (__attribute__((address_space(3))) unsigned int*)ldst, 16, 0, 0);
}

// ---------------- Router: fp32-exact logits, top-2, renorm weights, bins; fused x->bf16 --------
__global__ __launch_bounds__(256) void router_kernel(
    const float* __restrict__ x, const float* __restrict__ gw,
    float* __restrict__ logits, int* __restrict__ cnt,
    int* __restrict__ tok, float* __restrict__ wgt,
    unsigned short* __restrict__ xbf)
{
  const int t   = blockIdx.x;
  const int tid = threadIdx.x;
  float4 xv = ((const float4*)(x + (size_t)t * HIDDEN))[tid];
  if (xbf) {
    ushort4 o;
    o.x = f2bf(xv.x); o.y = f2bf(xv.y); o.z = f2bf(xv.z); o.w = f2bf(xv.w);
    ((ushort4*)(xbf + (size_t)t * HIDDEN))[tid] = o;
  }
  float p[NEXP];
#pragma unroll
  for (int e = 0; e < NEXP; ++e) {
    float4 gv = ((const float4*)(gw + (size_t)e * HIDDEN))[tid];
    p[e] = xv.x * gv.x + xv.y * gv.y + xv.z * gv.z + xv.w * gv.w;
  }
#pragma unroll
  for (int e = 0; e < NEXP; ++e) {
#pragma unroll
    for (int off = 32; off > 0; off >>= 1)
      p[e] += __shfl_down(p[e], off, 64);
  }
  __shared__ float red[4][NEXP];
  const int wv = tid >> 6, ln = tid & 63;
  if (ln == 0) {
#pragma unroll
    for (int e = 0; e < NEXP; ++e) red[wv][e] = p[e];
  }
  __syncthreads();
  if (tid == 0) {
    float l[NEXP];
#pragma unroll
    for (int e = 0; e < NEXP; ++e) {
      l[e] = red[0][e] + red[1][e] + red[2][e] + red[3][e];
      logits[(size_t)t * NEXP + e] = l[e];
    }
    int i0 = 0;
#pragma unroll
    for (int e = 1; e < NEXP; ++e) if (l[e] > l[i0]) i0 = e;
    int i1 = (i0 == 0) ? 1 : 0;
#pragma unroll
    for (int e = 0; e < NEXP; ++e) if (e != i0 && l[e] > l[i1]) i1 = e;
    float w0 = 1.f / (1.f + expf(l[i1] - l[i0]));
    float w1 = 1.f - w0;
    int s0 = atomicAdd(&cnt[i0], 1);
    tok[i0 * NTOK + s0] = t;  wgt[i0 * NTOK + s0] = w0;
    int s1 = atomicAdd(&cnt[i1], 1);
    tok[i1 * NTOK + s1] = t;  wgt[i1 * NTOK + s1] = w1;
  }
}

// ---------------- 128-padded per-expert row bases ----------------
__global__ void prefix_kernel(const int* __restrict__ cnt, int* __restrict__ base) {
  if (threadIdx.x == 0 && blockIdx.x == 0) {
    int b = 0;
#pragma unroll
    for (int e = 0; e < NEXP; ++e) { base[e] = b; b += ((cnt[e] + 127) >> 7) << 7; }
    base[NEXP] = b;
  }
}

// ---------------- fast fp32 -> bf16 for 3 weight tensors (full 16B stores) ----------------
__global__ __launch_bounds__(256) void cvtw_kernel(
    const float* __restrict__ s0, const float* __restrict__ s1, const float* __restrict__ s2,
    unsigned short* __restrict__ d0, unsigned short* __restrict__ d1, unsigned short* __restrict__ d2,
    int n8)   // groups of 8 floats per tensor
{
  const int start  = blockIdx.x * blockDim.x + threadIdx.x;
  const int stride = gridDim.x * blockDim.x;
#pragma unroll
  for (int pass = 0; pass < 3; ++pass) {
    const float* s = (pass == 0) ? s0 : (pass == 1) ? s1 : s2;
    unsigned short* d = (pass == 0) ? d0 : (pass == 1) ? d1 : d2;
    for (int i = start; i < n8; i += stride) {
      float4 a = ((const float4*)s)[2 * i];
      float4 b = ((const float4*)s)[2 * i + 1];
      ((uint4*)d)[i] = cvt8u(a, b);
    }
  }
}

// ---------------- GEMM1: H = silu(X W1^T) * (X W3^T), all-bf16 m97 -----------------------------
// M=128 x N=64 x BK=64, 512 thr (8 waves: 4M x 2N). All staging via g2l (4 instr/thread/step).
// LDS swizzle: [rows][8 units of 16B]; phys unit u of row r holds global unit u^(r&7)
// (source pre-swizzled, reads XOR the same key).
__global__ __launch_bounds__(512, 6) void gemm1_kernel(
    const unsigned short* __restrict__ xbf,   // [NTOK][HIDDEN] bf16
    const unsigned short* __restrict__ w1bf,  // [E][FFN][HIDDEN] bf16
    const unsigned short* __restrict__ w3bf,
    const int* __restrict__ cnt, const int* __restrict__ base,
    const int* __restrict__ tok,
    unsigned short* __restrict__ H)           // [MAXROWS][FFN] bf16
{
  // XCD-grouped: expert = bid%8 (one expert per XCD), mt fastest within XCD.
  const int bid  = blockIdx.x;
  const int e    = bid & 7;
  const int slot = bid >> 3;            // 0..511
  const int mt   = slot & 15;           // 128-row token tile
  const int nt   = slot >> 4;           // 0..31, 64-col ffn tile
  const int n = cnt[e];
  if (mt * 128 >= n) return;
  const int t = threadIdx.x;
  const int w = t >> 6, l = t & 63;

  __shared__ unsigned short Xs [128 * 64];   // 16 KB
  __shared__ unsigned short W1s[64 * 64];    // 8 KB
  __shared__ unsigned short W3s[64 * 64];    // 8 KB

  const int sr   = t >> 3;                        // staged row 0..63
  const int kp   = ((t & 7) ^ (sr & 7)) << 3;     // pre-swizzled k-elem offset
  const unsigned short* xp0 = xbf + (size_t)tok[e * NTOK + min(mt * 128 + sr, n - 1)]      * HIDDEN + kp;
  const unsigned short* xp1 = xbf + (size_t)tok[e * NTOK + min(mt * 128 + 64 + sr, n - 1)] * HIDDEN + kp;
  const unsigned short* w1p = w1bf + (size_t)e * FFN_DIM * HIDDEN + ((size_t)nt * 64 + sr) * HIDDEN + kp;
  const unsigned short* w3p = w3bf + (size_t)e * FFN_DIM * HIDDEN + ((size_t)nt * 64 + sr) * HIDDEN + kp;

  f32x4 acc1[2][2], acc3[2][2];
#pragma unroll
  for (int i = 0; i < 2; ++i)
#pragma unroll
    for (int j = 0; j < 2; ++j) { acc1[i][j] = (f32x4)0.f; acc3[i][j] = (f32x4)0.f; }

  const int Moff = (w & 3) * 32;        // 4 waves over M=128
  const int Noff = (w >> 2) * 32;       // 2 waves over N=64
  const int lr = l & 15;
  const int lg = l >> 4;

  for (int kb = 0; kb < HIDDEN / 64; ++kb) {
    __syncthreads();                    // previous compute done with LDS
    const int ko = kb * 64;
    ld_g2l16(xp0 + ko, (char*)Xs + w * 1024);           // rows 0..63
    ld_g2l16(xp1 + ko, (char*)Xs + 8192 + w * 1024);    // rows 64..127
    ld_g2l16(w1p + ko, (char*)W1s + w * 1024);
    ld_g2l16(w3p + ko, (char*)W3s + w * 1024);
    __syncthreads();                    // drains vmcnt -> LDS ready
#pragma unroll
    for (int s = 0; s < 2; ++s) {
      const int ub = 4 * s + lg;        // global k-unit this fragment wants
      bf16x8 a[2], b1[2], b3[2];
#pragma unroll
      for (int mi = 0; mi < 2; ++mi) {
        const int R = Moff + mi * 16 + lr;
        a[mi] = *(const bf16x8*)((const char*)Xs + R * 128 + ((ub ^ (R & 7)) << 4));
      }
#pragma unroll
      for (int ni = 0; ni < 2; ++ni) {
        const int R = Noff + ni * 16 + lr;
        b1[ni] = *(const bf16x8*)((const char*)W1s + R * 128 + ((ub ^ (R & 7)) << 4));
        b3[ni] = *(const bf16x8*)((const char*)W3s + R * 128 + ((ub ^ (R & 7)) << 4));
      }
#pragma unroll
      for (int mi = 0; mi < 2; ++mi)
#pragma unroll
        for (int ni = 0; ni < 2; ++ni) {
          acc1[mi][ni] = __builtin_amdgcn_mfma_f32_16x16x32_bf16(a[mi], b1[ni], acc1[mi][ni], 0, 0, 0);
          acc3[mi][ni] = __builtin_amdgcn_mfma_f32_16x16x32_bf16(a[mi], b3[ni], acc3[mi][ni], 0, 0, 0);
        }
    }
  }

  const size_t rbase = (size_t)base[e] + (size_t)mt * 128;
#pragma unroll
  for (int mi = 0; mi < 2; ++mi)
#pragma unroll
    for (int ni = 0; ni < 2; ++ni)
#pragma unroll
      for (int j = 0; j < 4; ++j) {
        int row = Moff + mi * 16 + lg * 4 + j;
        int col = nt * 64 + Noff + ni * 16 + lr;
        float s1 = acc1[mi][ni][j], s3 = acc3[mi][ni][j];
        float h = (s1 / (1.f + __expf(-s1))) * s3;      // silu(s1)*s3
        H[(rbase + row) * FFN_DIM + col] = f2bf(h);
      }
}

// ---------------- GEMM2: Y = H W2^T, M=128 x N=64 x BK=64, split-K x2, all-bf16 ---------------
__global__ __launch_bounds__(512, 6) void gemm2_kernel(
    const unsigned short* __restrict__ H,
    const unsigned short* __restrict__ w2bf,  // [E][HIDDEN][FFN] bf16
    const int* __restrict__ cnt, const int* __restrict__ base,
    const int* __restrict__ tok, const float* __restrict__ wgt,
    float* __restrict__ out)
{
  const int bid  = blockIdx.x;
  const int e    = bid & 7;
  const int slot = bid >> 3;            // 0..511
  const int mt   = slot & 15;           // 128-row token tile
  const int nt   = (slot >> 4) & 15;    // 64-col hidden tile
  const int sk   = slot >> 8;           // split-K 0..1
  const int n = cnt[e];
  if (mt * 128 >= n) return;
  const int t = threadIdx.x;
  const int w = t >> 6, l = t & 63;

  __shared__ unsigned short Hs [128 * 64];   // 16 KB
  __shared__ unsigned short W2s[64 * 64];    // 8 KB
  __shared__ int   stok[128];
  __shared__ float swgt[128];

  if (t < 128) {
    int idx = mt * 128 + t;
    int ok = idx < n;
    stok[t] = ok ? tok[e * NTOK + idx] : -1;
    swgt[t] = ok ? wgt[e * NTOK + idx] : 0.f;
  }

  const int sr = t >> 3;
  const int kp = ((t & 7) ^ (sr & 7)) << 3;
  const unsigned short* hp0 = H + (size_t)(base[e] + mt * 128 + sr)      * FFN_DIM + sk * (FFN_DIM / 2) + kp;
  const unsigned short* hp1 = H + (size_t)(base[e] + mt * 128 + 64 + sr) * FFN_DIM + sk * (FFN_DIM / 2) + kp;
  const unsigned short* w2p = w2bf + (size_t)e * HIDDEN * FFN_DIM + ((size_t)nt * 64 + sr) * FFN_DIM
                                  + sk * (FFN_DIM / 2) + kp;

  f32x4 acc[2][2];
#pragma unroll
  for (int i = 0; i < 2; ++i)
#pragma unroll
    for (int j = 0; j < 2; ++j) acc[i][j] = (f32x4)0.f;

  const int Moff = (w & 3) * 32;
  const int Noff = (w >> 2) * 32;
  const int lr = l & 15;
  const int lg = l >> 4;

  for (int kb = 0; kb < FFN_DIM / 2 / 64; ++kb) {
    __syncthreads();
    const int ko = kb * 64;
    ld_g2l16(hp0 + ko, (char*)Hs + w * 1024);
    ld_g2l16(hp1 + ko, (char*)Hs + 8192 + w * 1024);
    ld_g2l16(w2p + ko, (char*)W2s + w * 1024);
    __syncthreads();
#pragma unroll
    for (int s = 0; s < 2; ++s) {
      const int ub = 4 * s + lg;
      bf16x8 a[2], b[2];
#pragma unroll
      for (int mi = 0; mi < 2; ++mi) {
        const int R = Moff + mi * 16 + lr;
        a[mi] = *(const bf16x8*)((const char*)Hs + R * 128 + ((ub ^ (R & 7)) << 4));
      }
#pragma unroll
      for (int ni = 0; ni < 2; ++ni) {
        const int R = Noff + ni * 16 + lr;
        b[ni] = *(const bf16x8*)((const char*)W2s + R * 128 + ((ub ^ (R & 7)) << 4));
      }
#pragma unroll
      for (int mi = 0; mi < 2; ++mi)
#pragma unroll
        for (int ni = 0; ni < 2; ++ni)
          acc[mi][ni] = __builtin_amdgcn_mfma_f32_16x16x32_bf16(a[mi], b[ni], acc[mi][ni], 0, 0, 0);
    }
  }

#pragma unroll
  for (int mi = 0; mi < 2; ++mi)
#pragma unroll
    for (int ni = 0; ni < 2; ++ni)
#pragma unroll
      for (int j = 0; j < 4; ++j) {
        int row = Moff + mi * 16 + lg * 4 + j;
        int tk = stok[row];
        if (tk >= 0) {
          int col = nt * 64 + Noff + ni * 16 + lr;
          atomicAdd(&out[(size_t)tk * HIDDEN + col], swgt[row] * acc[mi][ni][j]);
        }
      }
}

// ================= fp32 fallback path (used only if ws too small) =================
#define TT 12
#define FC 256
#define NCHUNK (FFN_DIM / FC)

__global__ __launch_bounds__(256) void moe_ffn_kernel(
    const float* __restrict__ x,
    const float* __restrict__ w1, const float* __restrict__ w2,
    const float* __restrict__ w3,
    const int* __restrict__ cnt, const int* __restrict__ tok,
    const float* __restrict__ wgt, float* __restrict__ out)
{
  const int e  = blockIdx.y;
  const int n  = cnt[e];
  const int ts = blockIdx.x * TT;
  if (ts >= n) return;
  const int tid = threadIdx.x;

  __shared__ float xs[TT * HIDDEN];
  __shared__ float hc[TT * FC];
  __shared__ int   stok[TT];
  __shared__ float swgt[TT];

  if (tid < TT) {
    int idx = ts + tid;
    int tk  = (idx < n) ? tok[e * NTOK + idx] : -1;
    stok[tid] = tk;
    swgt[tid] = (idx < n) ? wgt[e * NTOK + idx] : 0.f;
  }
  __syncthreads();
#pragma unroll
  for (int i = 0; i < TT; ++i) {
    int tk = stok[i];
    float4 v = make_float4(0.f, 0.f, 0.f, 0.f);
    if (tk >= 0) v = ((const float4*)(x + (size_t)tk * HIDDEN))[tid];
    ((float4*)(xs + i * HIDDEN))[tid] = v;
  }
  __syncthreads();

  const float* w1e = w1 + (size_t)e * FFN_DIM * HIDDEN;
  const float* w3e = w3 + (size_t)e * FFN_DIM * HIDDEN;
  const float* w2e = w2 + (size_t)e * HIDDEN * FFN_DIM;

  float yacc[4][TT];
#pragma unroll
  for (int j = 0; j < 4; ++j)
#pragma unroll
    for (int t = 0; t < TT; ++t) yacc[j][t] = 0.f;

  for (int c = 0; c < NCHUNK; ++c) {
    const int f = c * FC + tid;
    const float4* r1 = (const float4*)(w1e + (size_t)f * HIDDEN);
    const float4* r3 = (const float4*)(w3e + (size_t)f * HIDDEN);
    float a1[TT], a3[TT];
#pragma unroll
    for (int t = 0; t < TT; ++t) { a1[t] = 0.f; a3[t] = 0.f; }
    for (int k = 0; k < HIDDEN / 4; ++k) {
      float4 v1 = r1[k];
      float4 v3 = r3[k];
#pragma unroll
      for (int t = 0; t < TT; ++t) {
        float4 xv = *(const float4*)(xs + t * HIDDEN + 4 * k);
        a1[t] += xv.x * v1.x + xv.y * v1.y + xv.z * v1.z + xv.w * v1.w;
        a3[t] += xv.x * v3.x + xv.y * v3.y + xv.z * v3.z + xv.w * v3.w;
      }
    }
    __syncthreads();
#pragma unroll
    for (int t = 0; t < TT; ++t) {
      float g  = a1[t];
      float sg = g / (1.f + __expf(-g));
      hc[t * FC + tid] = sg * a3[t];
    }
    __syncthreads();
    const float4* r20 = (const float4*)(w2e + (size_t)(tid      ) * FFN_DIM + c * FC);
    const float4* r21 = (const float4*)(w2e + (size_t)(tid + 256) * FFN_DIM + c * FC);
    const float4* r22 = (const float4*)(w2e + (size_t)(tid + 512) * FFN_DIM + c * FC);
    const float4* r23 = (const float4*)(w2e + (size_t)(tid + 768) * FFN_DIM + c * FC);
    for (int k = 0; k < FC / 4; ++k) {
      float4 wv0 = r20[k], wv1 = r21[k], wv2 = r22[k], wv3 = r23[k];
#pragma unroll
      for (int t = 0; t < TT; ++t) {
        float4 hv = *(const float4*)(hc + t * FC + 4 * k);
        yacc[0][t] += hv.x * wv0.x + hv.y * wv0.y + hv.z * wv0.z + hv.w * wv0.w;
        yacc[1][t] += hv.x * wv1.x + hv.y * wv1.y + hv.z * wv1.z + hv.w * wv1.w;
        yacc[2][t] += hv.x * wv2.x + hv.y * wv2.y + hv.z * wv2.z + hv.w * wv2.w;
        yacc[3][t] += hv.x * wv3.x + hv.y * wv3.y + hv.z * wv3.z + hv.w * wv3.w;
      }
    }
  }

#pragma unroll
  for (int t = 0; t < TT; ++t) {
    int tk = stok[t];
    if (tk < 0) continue;
    float wt = swgt[t];
    float* orow = out + (size_t)tk * HIDDEN;
    atomicAdd(orow + tid,       wt * yacc[0][t]);
    atomicAdd(orow + tid + 256, wt * yacc[1][t]);
    atomicAdd(orow + tid + 512, wt * yacc[2][t]);
    atomicAdd(orow + tid + 768, wt * yacc[3][t]);
  }
}

extern "C" void kernel_launch(void* const* d_in, const int* in_sizes, int n_in,
                              void* d_out, int out_size, void* d_ws, size_t ws_size,
                              hipStream_t stream) {
  const float* x  = (const float*)d_in[0];
  const float* gw = (const float*)d_in[1];
  const float* w1 = (const float*)d_in[2];
  const float* w2 = (const float*)d_in[3];
  const float* w3 = (const float*)d_in[4];
  float* out    = (float*)d_out;
  float* logits = out + (size_t)NTOK * HIDDEN;

  char* ws = (char*)d_ws;
  int*   cnt  = (int*)(ws + OFF_CNT);
  int*   base = (int*)(ws + OFF_BASE);
  int*   tokp = (int*)(ws + OFF_TOK);
  float* wgtp = (float*)(ws + OFF_WGT);

  const bool big = (ws_size >= WS_NEED);
  unsigned short* xbf  = big ? (unsigned short*)(ws + OFF_XBF) : (unsigned short*)0;
  unsigned short* w1b  = big ? (unsigned short*)(ws + OFF_W1B) : (unsigned short*)0;
  unsigned short* w3b  = big ? (unsigned short*)(ws + OFF_W3B) : (unsigned short*)0;
  unsigned short* w2b  = big ? (unsigned short*)(ws + OFF_W2B) : (unsigned short*)0;
  unsigned short* Hbuf = big ? (unsigned short*)(ws + OFF_H)   : (unsigned short*)0;

  hipMemsetAsync(out, 0, (size_t)NTOK * HIDDEN * sizeof(float), stream);
  hipMemsetAsync(cnt, 0, NEXP * sizeof(int), stream);

  router_kernel<<<NTOK, 256, 0, stream>>>(x, gw, logits, cnt, tokp, wgtp, xbf);

  if (big) {
    cvtw_kernel<<<2048, 256, 0, stream>>>(w1, w3, w2, w1b, w3b, w2b,
                                          (int)((size_t)NEXP * FFN_DIM * HIDDEN / 8));
    prefix_kernel<<<1, 64, 0, stream>>>(cnt, base);

    gemm1_kernel<<<NEXP * 16 * 32, 512, 0, stream>>>(xbf, w1b, w3b, cnt, base, tokp, Hbuf);
    gemm2_kernel<<<NEXP * 16 * 16 * 2, 512, 0, stream>>>(Hbuf, w2b, cnt, base, tokp, wgtp, out);
  } else {
    dim3 grid((NTOK + TT - 1) / TT, NEXP);
    moe_ffn_kernel<<<grid, 256, 0, stream>>>(x, w1, w2, w3, cnt, tokp, wgtp, out);
  }
}